// Round 17
// baseline (521.900 us; speedup 1.0000x reference)
//
#include <hip/hip_runtime.h>

#define DIM 64
#define BIN_SHIFT 8          // 256 nodes per bin
#define BCAP 5120            // staging capacity per bin (mean 4092, +16 sigma)
#define NCLS 64              // degree classes (pdeg/8; Poisson(16) -> <=8 used)

typedef __attribute__((ext_vector_type(8))) _Float16 half8;
typedef __attribute__((ext_vector_type(4))) _Float16 half4;
typedef __attribute__((ext_vector_type(4))) float floatx4;

// ---------------------------------------------------------------------------
// Pass A: bin edges by col>>8 into per-bin staging with chunk reservation.
// ---------------------------------------------------------------------------
__launch_bounds__(256)
__global__ void bin_edges_kernel(const int* __restrict__ row,
                                 const int* __restrict__ col,
                                 int* __restrict__ bin_cursor,
                                 int2* __restrict__ staging, int E) {
    __shared__ int hist[512];
    __shared__ int base[512];
    int tid = threadIdx.x;
    for (int i = tid; i < 512; i += 256) hist[i] = 0;
    __syncthreads();
    int e0 = blockIdx.x * 4096;
    int c[16];
    #pragma unroll
    for (int k = 0; k < 16; ++k) {
        int e = e0 + tid + k * 256;
        c[k] = (e < E) ? col[e] : -1;
        if (c[k] >= 0) atomicAdd(&hist[c[k] >> BIN_SHIFT], 1);
    }
    __syncthreads();
    for (int i = tid; i < 512; i += 256) {
        base[i] = (hist[i] > 0) ? atomicAdd(&bin_cursor[i], hist[i]) : 0;
        hist[i] = 0;   // reuse as intra-block offset
    }
    __syncthreads();
    #pragma unroll
    for (int k = 0; k < 16; ++k) {
        if (c[k] >= 0) {
            int e = e0 + tid + k * 256;
            int b = c[k] >> BIN_SHIFT;
            int idx = atomicAdd(&hist[b], 1);
            staging[(size_t)b * BCAP + base[b] + idx] = make_int2(row[e], c[k]);
        }
    }
}

// ---------------------------------------------------------------------------
// Per-bin degree count + dinv/rdinv + padded chunk sum bs[b] + per-class
// histogram (cls = pdeg/8) for degree-sorted wave packing.
// pdeg = (deg+1+7)&~7  (self-edge included, pad to x8).
// ---------------------------------------------------------------------------
__launch_bounds__(256)
__global__ void count_deg_bins_kernel(const int2* __restrict__ staging,
                                      const int* __restrict__ bin_cursor,
                                      int* __restrict__ deg,
                                      float* __restrict__ dinv,
                                      float* __restrict__ rdinv,
                                      int* __restrict__ bs,
                                      int* __restrict__ cls_hist, int N) {
    __shared__ int hist[256];
    __shared__ int red[256];
    __shared__ int chist[NCLS];
    int b = blockIdx.x;
    int tid = threadIdx.x;
    hist[tid] = 0;
    if (tid < NCLS) chist[tid] = 0;
    __syncthreads();
    int cnt = bin_cursor[b];
    for (int i = tid; i < cnt; i += 256)
        atomicAdd(&hist[staging[(size_t)b * BCAP + i].y & 255], 1);
    __syncthreads();
    int n = (b << BIN_SHIFT) + tid;
    int pdeg = 0;
    if (n < N) {
        int dg = hist[tid];
        deg[n] = dg;
        float d = (float)dg + 1.0f;
        dinv[n] = rsqrtf(d);
        rdinv[n] = sqrtf(d);
        pdeg = (dg + 1 + 7) & ~7;
        int cls = pdeg >> 3;
        if (cls > NCLS - 1) cls = NCLS - 1;
        atomicAdd(&chist[cls], 1);
    }
    red[tid] = pdeg;
    __syncthreads();
    for (int d = 128; d > 0; d >>= 1) {
        if (tid < d) red[tid] += red[tid + d];
        __syncthreads();
    }
    if (tid == 0) bs[b] = red[0];
    if (tid < NCLS && chist[tid] > 0) atomicAdd(&cls_hist[tid], chist[tid]);
}

// exclusive scan of the 64 class counts -> cls_cursor (chunk-reserve bases)
__global__ void scan_classes_kernel(const int* __restrict__ cls_hist,
                                    int* __restrict__ cls_cursor) {
    int t = threadIdx.x;      // 64 threads
    // simple serial-ish scan in lane 0 (64 entries, trivial)
    if (t == 0) {
        int acc = 0;
        for (int i = 0; i < NCLS; ++i) {
            cls_cursor[i] = acc;
            acc += cls_hist[i];
        }
    }
}

// scatter nodes into order[] grouped by degree class (chunked reservation)
__launch_bounds__(256)
__global__ void scatter_order_kernel(const int* __restrict__ deg,
                                     int* __restrict__ cls_cursor,
                                     int* __restrict__ order, int N) {
    __shared__ int lh[NCLS];
    __shared__ int lb[NCLS];
    int tid = threadIdx.x;
    if (tid < NCLS) lh[tid] = 0;
    __syncthreads();
    int n = blockIdx.x * 256 + tid;
    int cls = 0, rank = 0;
    if (n < N) {
        int pdeg = (deg[n] + 1 + 7) & ~7;
        cls = pdeg >> 3;
        if (cls > NCLS - 1) cls = NCLS - 1;
        rank = atomicAdd(&lh[cls], 1);
    }
    __syncthreads();
    if (tid < NCLS)
        lb[tid] = (lh[tid] > 0) ? atomicAdd(&cls_cursor[tid], lh[tid]) : 0;
    __syncthreads();
    if (n < N) order[lb[cls] + rank] = n;
}

__global__ void scan_block_sums_kernel(int* __restrict__ bs, int nb) {
    __shared__ int s[1024];
    int t = threadIdx.x;
    s[t] = (t < nb) ? bs[t] : 0;
    __syncthreads();
    for (int d = 1; d < 1024; d <<= 1) {
        int v = (t >= d) ? s[t - d] : 0;
        __syncthreads();
        s[t] += v;
        __syncthreads();
    }
    if (t < nb) bs[t] = (t == 0) ? 0 : s[t - 1];
}

__global__ void scan_chunks_kernel(const int* __restrict__ deg,
                                   const int* __restrict__ bs,
                                   int* __restrict__ ptr, int N) {
    __shared__ int s[256];
    int b = blockIdx.x, t = threadIdx.x;
    int i = b * 256 + t;
    int v = (i < N) ? ((deg[i] + 1 + 7) & ~7) : 0;
    s[t] = v;
    __syncthreads();
    for (int d = 1; d < 256; d <<= 1) {
        int u = (t >= d) ? s[t - d] : 0;
        __syncthreads();
        s[t] += u;
        __syncthreads();
    }
    if (i < N) {
        int p = bs[b] + s[t] - v;
        ptr[i] = p;
        if (i == N - 1) ptr[N] = p + v;
    }
}

// ---------------------------------------------------------------------------
// Pass B: one block per bin; LDS cursors. Bucket = self-edge n, in-edges,
// dummy-N padding to x8.
// ---------------------------------------------------------------------------
__launch_bounds__(256)
__global__ void fill_bins_kernel(const int2* __restrict__ staging,
                                 const int* __restrict__ bin_cursor,
                                 const int* __restrict__ ptr,
                                 int* __restrict__ srcs, int N, int dummy) {
    __shared__ int cur[256];
    int b = blockIdx.x;
    int tid = threadIdx.x;
    int n = (b << BIN_SHIFT) + tid;
    if (n < N) {
        int p = ptr[n];
        srcs[p] = n;           // self-edge
        cur[tid] = p + 1;
    } else cur[tid] = 0;
    __syncthreads();
    int cnt = bin_cursor[b];
    for (int i = tid; i < cnt; i += 256) {
        int2 rc = staging[(size_t)b * BCAP + i];
        int pos = atomicAdd(&cur[rc.y & 255], 1);
        srcs[pos] = rc.x;
    }
    __syncthreads();
    if (n < N) {
        int e = cur[tid];            // == ptr[n] + 1 + deg[n]
        int stop = ptr[n + 1];
        for (; e < stop; ++e) srcs[e] = dummy;
    }
}

// ---------------------------------------------------------------------------
// scale_init: v0 (slab-major fp16 = dinv*x), x16 (row-major fp16), and
// dummy-row zeroing for all 6 slab buffers (tail threads).
// ---------------------------------------------------------------------------
__global__ void scale_init_slab_kernel(const float* __restrict__ x,
                                       const float* __restrict__ dinv,
                                       _Float16* __restrict__ v0,
                                       _Float16* __restrict__ x16,
                                       _Float16* __restrict__ v1,
                                       _Float16* __restrict__ v3,
                                       _Float16* __restrict__ v7,
                                       _Float16* __restrict__ T1,
                                       _Float16* __restrict__ T2, int N) {
    int t = blockIdx.x * blockDim.x + threadIdx.x;
    if (t < N * 16) {
        int n = t >> 4, d4 = (t & 15) * 4;
        float d = dinv[n];
        float4 a = *(const float4*)(x + (size_t)n * DIM + d4);
        half4 hx;
        hx.x = (_Float16)a.x; hx.y = (_Float16)a.y;
        hx.z = (_Float16)a.z; hx.w = (_Float16)a.w;
        *(half4*)(x16 + (size_t)n * DIM + d4) = hx;
        half4 hv;
        hv.x = (_Float16)(a.x * d); hv.y = (_Float16)(a.y * d);
        hv.z = (_Float16)(a.z * d); hv.w = (_Float16)(a.w * d);
        int slab = d4 >> 4, off = d4 & 15;
        *(half4*)(v0 + ((size_t)slab * (N + 1) + n) * 16 + off) = hv;
    } else {
        int extra = t - N * 16;      // 96 half4 slots: 6 buffers x 64 halves
        if (extra < 96) {
            _Float16* bufs[6] = {v0, v1, v3, v7, T1, T2};
            int bf = extra >> 4;
            int r = (extra & 15) * 4;
            int slab = r >> 4, off = r & 15;
            half4 z = {(_Float16)0.f, (_Float16)0.f,
                       (_Float16)0.f, (_Float16)0.f};
            *(half4*)(bufs[bf] + ((size_t)slab * (N + 1) + N) * 16 + off) = z;
        }
    }
}

// ---------------------------------------------------------------------------
// Slab-major v-space propagate, XCD-pinned slabs (slab = (blockIdx&7)>>1),
// DEGREE-SORTED wave packing: wave processes order[idx..idx+3] — all 4
// nodes share the same padded bucket length (cls = pdeg/8), so the masked
// main loop has zero divergence waste (trip count mean-driven, not
// max-driven). Buckets: self-edge + in-edges + dummy pads, x8.
// 4-deep gather pipeline + fp16 pairwise tree-add.
// ---------------------------------------------------------------------------
__launch_bounds__(256)
__global__ void spmv_slab_kernel(const int* __restrict__ ptr,
                                 const int* __restrict__ srcs,
                                 const int* __restrict__ order,
                                 const float* __restrict__ dinv,
                                 const _Float16* __restrict__ vin,
                                 _Float16* __restrict__ vout,
                                 int N, int bps) {
    int b = blockIdx.x;
    int slab = (b & 7) >> 1;                 // XCD pair -> slab
    int blk  = ((b >> 3) << 1) | (b & 1);    // index within slab
    if (blk >= bps) return;
    const _Float16* vi = vin + (size_t)slab * (N + 1) * 16;
    _Float16* vo = vout + (size_t)slab * (N + 1) * 16;
    int tid = threadIdx.x;
    int lane = tid & 63;
    int q = lane >> 4;            // node sub-slot 0..3
    int e2 = (lane >> 1) & 7;     // edge slot 0..7
    int h = lane & 1;             // 16B half of the 32B row
    int idx = (blk * 4 + (tid >> 6)) * 4 + q;
    bool valid = idx < N;
    int n = valid ? order[idx] : 0;
    int beg = valid ? ptr[n] : 0;
    int end = valid ? ptr[n + 1] : 0;

    float a[8];
    #pragma unroll
    for (int k = 0; k < 8; ++k) a[k] = 0.f;

    // 4-deep pipeline: indices for 4 groups always ready before gathers.
    int s0 = srcs[beg + e2];
    int s1 = srcs[beg + 8 + e2];
    int s2 = srcs[beg + 16 + e2];
    int s3 = srcs[beg + 24 + e2];
    int j = beg;
    for (; j + 32 <= end; j += 32) {
        half8 h0 = *(const half8*)(vi + ((size_t)s0 << 4) + (h << 3));
        half8 h1 = *(const half8*)(vi + ((size_t)s1 << 4) + (h << 3));
        half8 h2 = *(const half8*)(vi + ((size_t)s2 << 4) + (h << 3));
        half8 h3 = *(const half8*)(vi + ((size_t)s3 << 4) + (h << 3));
        s0 = srcs[j + 32 + e2];
        s1 = srcs[j + 40 + e2];
        s2 = srcs[j + 48 + e2];
        s3 = srcs[j + 56 + e2];
        half8 g = (h0 + h1) + (h2 + h3);   // fp16 tree (v_pk_add_f16)
        #pragma unroll
        for (int k = 0; k < 8; ++k) a[k] += (float)g[k];
    }
    int rem = end - j;
    if (rem >= 16) {
        half8 h0 = *(const half8*)(vi + ((size_t)s0 << 4) + (h << 3));
        half8 h1 = *(const half8*)(vi + ((size_t)s1 << 4) + (h << 3));
        half8 g = h0 + h1;
        #pragma unroll
        for (int k = 0; k < 8; ++k) a[k] += (float)g[k];
        s0 = s2;
        rem -= 16;
    }
    if (rem >= 8) {
        half8 h0 = *(const half8*)(vi + ((size_t)s0 << 4) + (h << 3));
        #pragma unroll
        for (int k = 0; k < 8; ++k) a[k] += (float)h0[k];
    }

    #pragma unroll
    for (int k = 0; k < 8; ++k) {
        a[k] += __shfl_xor(a[k], 2);
        a[k] += __shfl_xor(a[k], 4);
        a[k] += __shfl_xor(a[k], 8);
    }
    if (e2 == 0 && valid) {
        float d = dinv[n];
        float dd = d * d;
        half8 r;
        #pragma unroll
        for (int k = 0; k < 8; ++k)
            r[k] = (_Float16)(dd * a[k]);
        *(half8*)(vo + ((size_t)n << 4) + (h << 3)) = r;
    }
}

// ---------------------------------------------------------------------------
// make_wfrag: folded effective weights, fp16, in exact MFMA B-fragment order
// wf[((dt*8 + t)*64 + lane)*8 + j]. Fold (reference quirk: powers cumulative
// -> x_agg = {x, Ax, A^3x, A^7x}):
//   cat@W = x@W3 + p1@(W0-W3+W4) + p3@(W1-W4+W5) + p7@(W2-W5)
// ---------------------------------------------------------------------------
__global__ void make_wfrag_kernel(const float* __restrict__ W,
                                  _Float16* __restrict__ wf) {
    int idx = blockIdx.x * blockDim.x + threadIdx.x;   // 16384
    if (idx < 16384) {
        int j = idx & 7;
        int lane = (idx >> 3) & 63;
        int t = (idx >> 9) & 7;
        int dt = idx >> 12;
        int col = lane & 15, quad = lane >> 4;
        int d = dt * 16 + col;
        int kk = t * 32 + quad * 8 + j;
        int src = kk >> 6, k = kk & 63;
        float v;
        if (src == 0)      v = W[(3 * 64 + k) * 64 + d];
        else if (src == 1) v = W[(0 * 64 + k) * 64 + d]
                             - W[(3 * 64 + k) * 64 + d]
                             + W[(4 * 64 + k) * 64 + d];
        else if (src == 2) v = W[(1 * 64 + k) * 64 + d]
                             - W[(4 * 64 + k) * 64 + d]
                             + W[(5 * 64 + k) * 64 + d];
        else               v = W[(2 * 64 + k) * 64 + d]
                             - W[(5 * 64 + k) * 64 + d];
        wf[idx] = (_Float16)v;
    }
}

// ---------------------------------------------------------------------------
// MFMA combine v4: no LDS, no syncthreads. A-fragments direct from global
// (half8 in A-layout, rdinv applied as fp16 scale); B-fragments direct from
// the 32 KB fragment-ordered wf table (L1/L2-hot, coalesced). One wave = one
// 16-node group, all 64 output dims (32 mfma).
// Verified layouts: A/B row = lane&15, k = quad*8+j; D col=lane&15,
// row=quad*4+reg.
// ---------------------------------------------------------------------------
__launch_bounds__(256)
__global__ void combine_mfma_kernel(const _Float16* __restrict__ x16,
                                    const _Float16* __restrict__ v1,
                                    const _Float16* __restrict__ v3,
                                    const _Float16* __restrict__ v7,
                                    const float* __restrict__ rdinv,
                                    const _Float16* __restrict__ wf,
                                    const float* __restrict__ bias,
                                    float* __restrict__ out, int N) {
    int tid = threadIdx.x;
    int lane = tid & 63, w = tid >> 6;
    int quad = lane >> 4, col = lane & 15;

    float bv[4];
    #pragma unroll
    for (int dt = 0; dt < 4; ++dt) bv[dt] = bias[dt * 16 + col];

    int bps = (N + 15) / 16;
    size_t N1 = (size_t)N + 1;
    for (int g = blockIdx.x * 4 + w; g < bps; g += gridDim.x * 4) {
        int n0 = g * 16;
        int n = n0 + col;
        int nl = (n < N) ? n : 0;
        _Float16 hrd = (_Float16)rdinv[nl];

        half8 a[8];
        a[0] = *(const half8*)(x16 + (size_t)nl * DIM + quad * 8);
        a[1] = *(const half8*)(x16 + (size_t)nl * DIM + 32 + quad * 8);
        const _Float16* vs[3] = {v1, v3, v7};
        #pragma unroll
        for (int sI = 0; sI < 3; ++sI) {
            #pragma unroll
            for (int hf = 0; hf < 2; ++hf) {
                int d0 = hf * 32 + quad * 8;
                int slab = d0 >> 4, off = d0 & 15;
                half8 hv = *(const half8*)(vs[sI] + ((size_t)slab * N1 + nl) * 16 + off);
                #pragma unroll
                for (int j = 0; j < 8; ++j) hv[j] = hv[j] * hrd;
                a[2 + sI * 2 + hf] = hv;
            }
        }

        floatx4 acc[4];
        #pragma unroll
        for (int dt = 0; dt < 4; ++dt) {
            floatx4 z = {bv[dt], bv[dt], bv[dt], bv[dt]};
            acc[dt] = z;
        }
        #pragma unroll
        for (int t = 0; t < 8; ++t) {
            #pragma unroll
            for (int dt = 0; dt < 4; ++dt) {
                half8 bf = *(const half8*)(wf + (((dt * 8 + t) * 64 + lane) << 3));
                acc[dt] = __builtin_amdgcn_mfma_f32_16x16x32_f16(
                    a[t], bf, acc[dt], 0, 0, 0);
            }
        }

        #pragma unroll
        for (int dt = 0; dt < 4; ++dt)
            #pragma unroll
            for (int r = 0; r < 4; ++r) {
                int nn = n0 + quad * 4 + r;
                if (nn < N)
                    out[(size_t)nn * DIM + dt * 16 + col] =
                        fmaxf(acc[dt][r], 0.f);
            }
    }
}

extern "C" void kernel_launch(void* const* d_in, const int* in_sizes, int n_in,
                              void* d_out, int out_size, void* d_ws, size_t ws_size,
                              hipStream_t stream) {
    const float* x  = (const float*)d_in[0];
    const int*   ei = (const int*)d_in[1];
    const float* W  = (const float*)d_in[2];
    const float* b  = (const float*)d_in[3];
    float* out = (float*)d_out;

    const int N = in_sizes[0] / DIM;
    const int E = in_sizes[1] / 2;
    const int* row = ei;
    const int* col = ei + E;

    const int nbins = (N + 255) >> BIN_SHIFT;
    int bps = (N + 15) / 16;              // blocks per slab for spmv
    if (bps & 1) ++bps;                   // even for the swizzle bijection
    const size_t SLABSZ = (size_t)4 * (N + 1) * 16;   // halves per buffer

    int2* staging = (int2*)d_ws;                          // 512*BCAP
    float* dinv  = (float*)(staging + (size_t)512 * BCAP);
    float* rdinv = dinv + N;
    _Float16* wf  = (_Float16*)(rdinv + N);               // 16384 halves
    _Float16* x16 = wf + 16384;                           // (N+16)*64
    _Float16* v0 = x16 + (size_t)(N + 16) * 64;
    _Float16* v1 = v0 + SLABSZ;
    _Float16* v3 = v1 + SLABSZ;
    _Float16* v7 = v3 + SLABSZ;
    _Float16* T1 = v7 + SLABSZ;
    _Float16* T2 = T1 + SLABSZ;
    int* deg = (int*)(T2 + SLABSZ);       // N
    int* ptr = deg + N;                   // N+1
    int* bs  = ptr + N + 1;               // <=1024
    int* bin_cursor = bs + 1024;          // 512
    int* cls_hist   = bin_cursor + 512;   // 64  (zeroed with bin_cursor)
    int* cls_cursor = cls_hist + 64;      // 64
    int* order      = cls_cursor + 64;    // N
    int* srcs       = order + N;          // E + 8N + 64 tail pad

    // --- bin edges (zero bin_cursor + cls_hist together: 576 ints) ---
    hipMemsetAsync(bin_cursor, 0, 576 * sizeof(int), stream);
    bin_edges_kernel<<<(E + 4095) / 4096, 256, 0, stream>>>(row, col,
                                                            bin_cursor,
                                                            staging, E);
    // --- per-bin degree + dinv/rdinv + chunk sums + class histogram ---
    count_deg_bins_kernel<<<nbins, 256, 0, stream>>>(staging, bin_cursor,
                                                     deg, dinv, rdinv, bs,
                                                     cls_hist, N);
    // --- degree-class order ---
    scan_classes_kernel<<<1, 64, 0, stream>>>(cls_hist, cls_cursor);
    scatter_order_kernel<<<nbins, 256, 0, stream>>>(deg, cls_cursor, order, N);
    // --- scan of chunk sums, then per-chunk prefix -> ptr ---
    scan_block_sums_kernel<<<1, 1024, 0, stream>>>(bs, nbins);
    scan_chunks_kernel<<<nbins, 256, 0, stream>>>(deg, bs, ptr, N);
    // --- CSC fill from bins (self-edge + edges + dummy pads) ---
    fill_bins_kernel<<<nbins, 256, 0, stream>>>(staging, bin_cursor, ptr,
                                                srcs, N, N);
    // --- fragment-ordered folded weights ---
    make_wfrag_kernel<<<64, 256, 0, stream>>>(W, wf);
    // --- v0 (slab-major) + x16 + dummy-row zeroing ---
    scale_init_slab_kernel<<<(N * 16 + 96 + 255) / 256, 256, 0, stream>>>(
        x, dinv, v0, x16, v1, v3, v7, T1, T2, N);

    auto prop = [&](const _Float16* src, _Float16* dst) {
        spmv_slab_kernel<<<4 * bps, 256, 0, stream>>>(ptr, srcs, order, dinv,
                                                      src, dst, N, bps);
    };
    prop(v0, v1);   // A^1
    prop(v1, T1);   // A^2
    prop(T1, v3);   // A^3
    prop(v3, T1);   // A^4
    prop(T1, T2);   // A^5
    prop(T2, T1);   // A^6
    prop(T1, v7);   // A^7

    // --- combine (MFMA, fragment-table B, direct A loads, no LDS) ---
    combine_mfma_kernel<<<1024, 256, 0, stream>>>(x16, v1, v3, v7, rdinv,
                                                  wf, b, out, N);
}

// Round 18
// 459.790 us; speedup vs baseline: 1.1351x; 1.1351x over previous
//
#include <hip/hip_runtime.h>

#define DIM 64
#define BIN_SHIFT 8          // 256 nodes per bin
#define BCAP 5120            // staging capacity per bin (mean 4092, +16 sigma)

typedef __attribute__((ext_vector_type(8))) _Float16 half8;
typedef __attribute__((ext_vector_type(4))) _Float16 half4;
typedef __attribute__((ext_vector_type(4))) float floatx4;

// ---------------------------------------------------------------------------
// Pass A: bin edges by col>>8 into per-bin staging with chunk reservation.
// ---------------------------------------------------------------------------
__launch_bounds__(256)
__global__ void bin_edges_kernel(const int* __restrict__ row,
                                 const int* __restrict__ col,
                                 int* __restrict__ bin_cursor,
                                 int2* __restrict__ staging, int E) {
    __shared__ int hist[512];
    __shared__ int base[512];
    int tid = threadIdx.x;
    for (int i = tid; i < 512; i += 256) hist[i] = 0;
    __syncthreads();
    int e0 = blockIdx.x * 4096;
    int c[16];
    #pragma unroll
    for (int k = 0; k < 16; ++k) {
        int e = e0 + tid + k * 256;
        c[k] = (e < E) ? col[e] : -1;
        if (c[k] >= 0) atomicAdd(&hist[c[k] >> BIN_SHIFT], 1);
    }
    __syncthreads();
    for (int i = tid; i < 512; i += 256) {
        base[i] = (hist[i] > 0) ? atomicAdd(&bin_cursor[i], hist[i]) : 0;
        hist[i] = 0;   // reuse as intra-block offset
    }
    __syncthreads();
    #pragma unroll
    for (int k = 0; k < 16; ++k) {
        if (c[k] >= 0) {
            int e = e0 + tid + k * 256;
            int b = c[k] >> BIN_SHIFT;
            int idx = atomicAdd(&hist[b], 1);
            staging[(size_t)b * BCAP + base[b] + idx] = make_int2(row[e], c[k]);
        }
    }
}

// ---------------------------------------------------------------------------
// Per-bin degree count + dinv/rdinv + padded chunk sum bs[b] (bins == scan
// chunks: 256 nodes). pdeg = (deg+1+7)&~7  (self-edge included, pad to x8).
// ---------------------------------------------------------------------------
__launch_bounds__(256)
__global__ void count_deg_bins_kernel(const int2* __restrict__ staging,
                                      const int* __restrict__ bin_cursor,
                                      int* __restrict__ deg,
                                      float* __restrict__ dinv,
                                      float* __restrict__ rdinv,
                                      int* __restrict__ bs, int N) {
    __shared__ int hist[256];
    __shared__ int red[256];
    int b = blockIdx.x;
    int tid = threadIdx.x;
    hist[tid] = 0;
    __syncthreads();
    int cnt = bin_cursor[b];
    for (int i = tid; i < cnt; i += 256)
        atomicAdd(&hist[staging[(size_t)b * BCAP + i].y & 255], 1);
    __syncthreads();
    int n = (b << BIN_SHIFT) + tid;
    int pdeg = 0;
    if (n < N) {
        int dg = hist[tid];
        deg[n] = dg;
        float d = (float)dg + 1.0f;
        dinv[n] = rsqrtf(d);
        rdinv[n] = sqrtf(d);
        pdeg = (dg + 1 + 7) & ~7;
    }
    red[tid] = pdeg;
    __syncthreads();
    for (int d = 128; d > 0; d >>= 1) {
        if (tid < d) red[tid] += red[tid + d];
        __syncthreads();
    }
    if (tid == 0) bs[b] = red[0];
}

__global__ void scan_block_sums_kernel(int* __restrict__ bs, int nb) {
    __shared__ int s[1024];
    int t = threadIdx.x;
    s[t] = (t < nb) ? bs[t] : 0;
    __syncthreads();
    for (int d = 1; d < 1024; d <<= 1) {
        int v = (t >= d) ? s[t - d] : 0;
        __syncthreads();
        s[t] += v;
        __syncthreads();
    }
    if (t < nb) bs[t] = (t == 0) ? 0 : s[t - 1];
}

__global__ void scan_chunks_kernel(const int* __restrict__ deg,
                                   const int* __restrict__ bs,
                                   int* __restrict__ ptr, int N) {
    __shared__ int s[256];
    int b = blockIdx.x, t = threadIdx.x;
    int i = b * 256 + t;
    int v = (i < N) ? ((deg[i] + 1 + 7) & ~7) : 0;
    s[t] = v;
    __syncthreads();
    for (int d = 1; d < 256; d <<= 1) {
        int u = (t >= d) ? s[t - d] : 0;
        __syncthreads();
        s[t] += u;
        __syncthreads();
    }
    if (i < N) {
        int p = bs[b] + s[t] - v;
        ptr[i] = p;
        if (i == N - 1) ptr[N] = p + v;
    }
}

// ---------------------------------------------------------------------------
// Pass B: one block per bin; LDS cursors. Bucket = self-edge n, in-edges,
// dummy-N padding to x8.
// ---------------------------------------------------------------------------
__launch_bounds__(256)
__global__ void fill_bins_kernel(const int2* __restrict__ staging,
                                 const int* __restrict__ bin_cursor,
                                 const int* __restrict__ ptr,
                                 int* __restrict__ srcs, int N, int dummy) {
    __shared__ int cur[256];
    int b = blockIdx.x;
    int tid = threadIdx.x;
    int n = (b << BIN_SHIFT) + tid;
    if (n < N) {
        int p = ptr[n];
        srcs[p] = n;           // self-edge
        cur[tid] = p + 1;
    } else cur[tid] = 0;
    __syncthreads();
    int cnt = bin_cursor[b];
    for (int i = tid; i < cnt; i += 256) {
        int2 rc = staging[(size_t)b * BCAP + i];
        int pos = atomicAdd(&cur[rc.y & 255], 1);
        srcs[pos] = rc.x;
    }
    __syncthreads();
    if (n < N) {
        int e = cur[tid];            // == ptr[n] + 1 + deg[n]
        int stop = ptr[n + 1];
        for (; e < stop; ++e) srcs[e] = dummy;
    }
}

// ---------------------------------------------------------------------------
// scale_init: v0 (slab-major fp16 = dinv*x), x16 (row-major fp16), and
// dummy-row zeroing for all 6 slab buffers (tail threads).
// ---------------------------------------------------------------------------
__global__ void scale_init_slab_kernel(const float* __restrict__ x,
                                       const float* __restrict__ dinv,
                                       _Float16* __restrict__ v0,
                                       _Float16* __restrict__ x16,
                                       _Float16* __restrict__ v1,
                                       _Float16* __restrict__ v3,
                                       _Float16* __restrict__ v7,
                                       _Float16* __restrict__ T1,
                                       _Float16* __restrict__ T2, int N) {
    int t = blockIdx.x * blockDim.x + threadIdx.x;
    if (t < N * 16) {
        int n = t >> 4, d4 = (t & 15) * 4;
        float d = dinv[n];
        float4 a = *(const float4*)(x + (size_t)n * DIM + d4);
        half4 hx;
        hx.x = (_Float16)a.x; hx.y = (_Float16)a.y;
        hx.z = (_Float16)a.z; hx.w = (_Float16)a.w;
        *(half4*)(x16 + (size_t)n * DIM + d4) = hx;
        half4 hv;
        hv.x = (_Float16)(a.x * d); hv.y = (_Float16)(a.y * d);
        hv.z = (_Float16)(a.z * d); hv.w = (_Float16)(a.w * d);
        int slab = d4 >> 4, off = d4 & 15;
        *(half4*)(v0 + ((size_t)slab * (N + 1) + n) * 16 + off) = hv;
    } else {
        int extra = t - N * 16;      // 96 half4 slots: 6 buffers x 64 halves
        if (extra < 96) {
            _Float16* bufs[6] = {v0, v1, v3, v7, T1, T2};
            int bf = extra >> 4;
            int r = (extra & 15) * 4;
            int slab = r >> 4, off = r & 15;
            half4 z = {(_Float16)0.f, (_Float16)0.f,
                       (_Float16)0.f, (_Float16)0.f};
            *(half4*)(bufs[bf] + ((size_t)slab * (N + 1) + N) * 16 + off) = z;
        }
    }
}

// ---------------------------------------------------------------------------
// Slab-major v-space propagate, XCD-pinned slabs (slab = (blockIdx&7)>>1:
// XCD pair {2s,2s+1} touches only slab s -> 3.2 MB L2-resident).
// Wave = 4 nodes in NATURAL order (adjacent buckets -> srcs/ptr locality;
// R17 proved order[] indirection costs more than divergence saves).
// Buckets: self-edge + in-edges + dummy pads (weight 1), x8, >= 8.
// 4-deep gather pipeline + fp16 pairwise tree-add (v_pk_add_f16).
// ---------------------------------------------------------------------------
__launch_bounds__(256)
__global__ void spmv_slab_kernel(const int* __restrict__ ptr,
                                 const int* __restrict__ srcs,
                                 const float* __restrict__ dinv,
                                 const _Float16* __restrict__ vin,
                                 _Float16* __restrict__ vout,
                                 int N, int bps) {
    int b = blockIdx.x;
    int slab = (b & 7) >> 1;                 // XCD pair -> slab
    int blk  = ((b >> 3) << 1) | (b & 1);    // index within slab
    if (blk >= bps) return;
    const _Float16* vi = vin + (size_t)slab * (N + 1) * 16;
    _Float16* vo = vout + (size_t)slab * (N + 1) * 16;
    int tid = threadIdx.x;
    int lane = tid & 63;
    int q = lane >> 4;            // node sub-slot 0..3
    int e2 = (lane >> 1) & 7;     // edge slot 0..7
    int h = lane & 1;             // 16B half of the 32B row
    int n = (blk * 4 + (tid >> 6)) * 4 + q;
    bool valid = n < N;
    int beg = valid ? ptr[n] : 0;
    int end = valid ? ptr[n + 1] : 0;

    float a[8];
    #pragma unroll
    for (int k = 0; k < 8; ++k) a[k] = 0.f;

    // 4-deep pipeline: indices for 4 groups always ready before gathers.
    int s0 = srcs[beg + e2];
    int s1 = srcs[beg + 8 + e2];
    int s2 = srcs[beg + 16 + e2];
    int s3 = srcs[beg + 24 + e2];
    int j = beg;
    for (; j + 32 <= end; j += 32) {
        half8 h0 = *(const half8*)(vi + ((size_t)s0 << 4) + (h << 3));
        half8 h1 = *(const half8*)(vi + ((size_t)s1 << 4) + (h << 3));
        half8 h2 = *(const half8*)(vi + ((size_t)s2 << 4) + (h << 3));
        half8 h3 = *(const half8*)(vi + ((size_t)s3 << 4) + (h << 3));
        s0 = srcs[j + 32 + e2];
        s1 = srcs[j + 40 + e2];
        s2 = srcs[j + 48 + e2];
        s3 = srcs[j + 56 + e2];
        half8 g = (h0 + h1) + (h2 + h3);   // fp16 tree (v_pk_add_f16)
        #pragma unroll
        for (int k = 0; k < 8; ++k) a[k] += (float)g[k];
    }
    int rem = end - j;
    if (rem >= 16) {
        half8 h0 = *(const half8*)(vi + ((size_t)s0 << 4) + (h << 3));
        half8 h1 = *(const half8*)(vi + ((size_t)s1 << 4) + (h << 3));
        half8 g = h0 + h1;
        #pragma unroll
        for (int k = 0; k < 8; ++k) a[k] += (float)g[k];
        s0 = s2;
        rem -= 16;
    }
    if (rem >= 8) {
        half8 h0 = *(const half8*)(vi + ((size_t)s0 << 4) + (h << 3));
        #pragma unroll
        for (int k = 0; k < 8; ++k) a[k] += (float)h0[k];
    }

    #pragma unroll
    for (int k = 0; k < 8; ++k) {
        a[k] += __shfl_xor(a[k], 2);
        a[k] += __shfl_xor(a[k], 4);
        a[k] += __shfl_xor(a[k], 8);
    }
    if (e2 == 0 && valid) {
        float d = dinv[n];
        float dd = d * d;
        half8 r;
        #pragma unroll
        for (int k = 0; k < 8; ++k)
            r[k] = (_Float16)(dd * a[k]);
        *(half8*)(vo + ((size_t)n << 4) + (h << 3)) = r;
    }
}

// ---------------------------------------------------------------------------
// make_wfrag: folded effective weights, fp16, in exact MFMA B-fragment order
// wf[((dt*8 + t)*64 + lane)*8 + j]  (lane = quad*16+col), so each combine
// B-load is one fully-coalesced 1 KB wave read of a 32 KB L1/L2-hot table.
// Fold (reference quirk: powers cumulative -> x_agg = {x, Ax, A^3x, A^7x}):
//   cat@W = x@W3 + p1@(W0-W3+W4) + p3@(W1-W4+W5) + p7@(W2-W5)
// ---------------------------------------------------------------------------
__global__ void make_wfrag_kernel(const float* __restrict__ W,
                                  _Float16* __restrict__ wf) {
    int idx = blockIdx.x * blockDim.x + threadIdx.x;   // 16384
    if (idx < 16384) {
        int j = idx & 7;
        int lane = (idx >> 3) & 63;
        int t = (idx >> 9) & 7;
        int dt = idx >> 12;
        int col = lane & 15, quad = lane >> 4;
        int d = dt * 16 + col;
        int kk = t * 32 + quad * 8 + j;
        int src = kk >> 6, k = kk & 63;
        float v;
        if (src == 0)      v = W[(3 * 64 + k) * 64 + d];
        else if (src == 1) v = W[(0 * 64 + k) * 64 + d]
                             - W[(3 * 64 + k) * 64 + d]
                             + W[(4 * 64 + k) * 64 + d];
        else if (src == 2) v = W[(1 * 64 + k) * 64 + d]
                             - W[(4 * 64 + k) * 64 + d]
                             + W[(5 * 64 + k) * 64 + d];
        else               v = W[(2 * 64 + k) * 64 + d]
                             - W[(5 * 64 + k) * 64 + d];
        wf[idx] = (_Float16)v;
    }
}

// ---------------------------------------------------------------------------
// MFMA combine v4: no LDS, no syncthreads. A-fragments direct from global
// (half8 in A-layout, rdinv applied as fp16 scale); B-fragments direct from
// the 32 KB fragment-ordered wf table (L1/L2-hot, coalesced). One wave = one
// 16-node group, all 64 output dims (32 mfma).
// Verified layouts: A/B row = lane&15, k = quad*8+j; D col=lane&15,
// row=quad*4+reg.
// ---------------------------------------------------------------------------
__launch_bounds__(256)
__global__ void combine_mfma_kernel(const _Float16* __restrict__ x16,
                                    const _Float16* __restrict__ v1,
                                    const _Float16* __restrict__ v3,
                                    const _Float16* __restrict__ v7,
                                    const float* __restrict__ rdinv,
                                    const _Float16* __restrict__ wf,
                                    const float* __restrict__ bias,
                                    float* __restrict__ out, int N) {
    int tid = threadIdx.x;
    int lane = tid & 63, w = tid >> 6;
    int quad = lane >> 4, col = lane & 15;

    float bv[4];
    #pragma unroll
    for (int dt = 0; dt < 4; ++dt) bv[dt] = bias[dt * 16 + col];

    int bps = (N + 15) / 16;
    size_t N1 = (size_t)N + 1;
    for (int g = blockIdx.x * 4 + w; g < bps; g += gridDim.x * 4) {
        int n0 = g * 16;
        int n = n0 + col;
        int nl = (n < N) ? n : 0;
        _Float16 hrd = (_Float16)rdinv[nl];

        half8 a[8];
        a[0] = *(const half8*)(x16 + (size_t)nl * DIM + quad * 8);
        a[1] = *(const half8*)(x16 + (size_t)nl * DIM + 32 + quad * 8);
        const _Float16* vs[3] = {v1, v3, v7};
        #pragma unroll
        for (int sI = 0; sI < 3; ++sI) {
            #pragma unroll
            for (int hf = 0; hf < 2; ++hf) {
                int d0 = hf * 32 + quad * 8;
                int slab = d0 >> 4, off = d0 & 15;
                half8 hv = *(const half8*)(vs[sI] + ((size_t)slab * N1 + nl) * 16 + off);
                #pragma unroll
                for (int j = 0; j < 8; ++j) hv[j] = hv[j] * hrd;
                a[2 + sI * 2 + hf] = hv;
            }
        }

        floatx4 acc[4];
        #pragma unroll
        for (int dt = 0; dt < 4; ++dt) {
            floatx4 z = {bv[dt], bv[dt], bv[dt], bv[dt]};
            acc[dt] = z;
        }
        #pragma unroll
        for (int t = 0; t < 8; ++t) {
            #pragma unroll
            for (int dt = 0; dt < 4; ++dt) {
                half8 bf = *(const half8*)(wf + (((dt * 8 + t) * 64 + lane) << 3));
                acc[dt] = __builtin_amdgcn_mfma_f32_16x16x32_f16(
                    a[t], bf, acc[dt], 0, 0, 0);
            }
        }

        #pragma unroll
        for (int dt = 0; dt < 4; ++dt)
            #pragma unroll
            for (int r = 0; r < 4; ++r) {
                int nn = n0 + quad * 4 + r;
                if (nn < N)
                    out[(size_t)nn * DIM + dt * 16 + col] =
                        fmaxf(acc[dt][r], 0.f);
            }
    }
}

extern "C" void kernel_launch(void* const* d_in, const int* in_sizes, int n_in,
                              void* d_out, int out_size, void* d_ws, size_t ws_size,
                              hipStream_t stream) {
    const float* x  = (const float*)d_in[0];
    const int*   ei = (const int*)d_in[1];
    const float* W  = (const float*)d_in[2];
    const float* b  = (const float*)d_in[3];
    float* out = (float*)d_out;

    const int N = in_sizes[0] / DIM;
    const int E = in_sizes[1] / 2;
    const int* row = ei;
    const int* col = ei + E;

    const int nbins = (N + 255) >> BIN_SHIFT;
    int bps = (N + 15) / 16;              // blocks per slab for spmv
    if (bps & 1) ++bps;                   // even for the swizzle bijection
    const size_t SLABSZ = (size_t)4 * (N + 1) * 16;   // halves per buffer

    int2* staging = (int2*)d_ws;                          // 512*BCAP
    float* dinv  = (float*)(staging + (size_t)512 * BCAP);
    float* rdinv = dinv + N;
    _Float16* wf  = (_Float16*)(rdinv + N);               // 16384 halves
    _Float16* x16 = wf + 16384;                           // (N+16)*64
    _Float16* v0 = x16 + (size_t)(N + 16) * 64;
    _Float16* v1 = v0 + SLABSZ;
    _Float16* v3 = v1 + SLABSZ;
    _Float16* v7 = v3 + SLABSZ;
    _Float16* T1 = v7 + SLABSZ;
    _Float16* T2 = T1 + SLABSZ;
    int* deg = (int*)(T2 + SLABSZ);       // N
    int* ptr = deg + N;                   // N+1
    int* bs  = ptr + N + 1;               // <=1024
    int* bin_cursor = bs + 1024;          // 512
    int* srcs = bin_cursor + 512;         // E + 8N + 64 tail pad

    // --- bin edges ---
    hipMemsetAsync(bin_cursor, 0, 512 * sizeof(int), stream);
    bin_edges_kernel<<<(E + 4095) / 4096, 256, 0, stream>>>(row, col,
                                                            bin_cursor,
                                                            staging, E);
    // --- per-bin degree + dinv/rdinv + padded chunk sums ---
    count_deg_bins_kernel<<<nbins, 256, 0, stream>>>(staging, bin_cursor,
                                                     deg, dinv, rdinv, bs, N);
    // --- scan of chunk sums, then per-chunk prefix -> ptr ---
    scan_block_sums_kernel<<<1, 1024, 0, stream>>>(bs, nbins);
    scan_chunks_kernel<<<nbins, 256, 0, stream>>>(deg, bs, ptr, N);
    // --- CSC fill from bins (self-edge + edges + dummy pads) ---
    fill_bins_kernel<<<nbins, 256, 0, stream>>>(staging, bin_cursor, ptr,
                                                srcs, N, N);
    // --- fragment-ordered folded weights ---
    make_wfrag_kernel<<<64, 256, 0, stream>>>(W, wf);
    // --- v0 (slab-major) + x16 + dummy-row zeroing ---
    scale_init_slab_kernel<<<(N * 16 + 96 + 255) / 256, 256, 0, stream>>>(
        x, dinv, v0, x16, v1, v3, v7, T1, T2, N);

    auto prop = [&](const _Float16* src, _Float16* dst) {
        spmv_slab_kernel<<<4 * bps, 256, 0, stream>>>(ptr, srcs, dinv,
                                                      src, dst, N, bps);
    };
    prop(v0, v1);   // A^1
    prop(v1, T1);   // A^2
    prop(T1, v3);   // A^3
    prop(v3, T1);   // A^4
    prop(T1, T2);   // A^5
    prop(T2, T1);   // A^6
    prop(T1, v7);   // A^7

    // --- combine (MFMA, fragment-table B, direct A loads, no LDS) ---
    combine_mfma_kernel<<<1024, 256, 0, stream>>>(x16, v1, v3, v7, rdinv,
                                                  wf, b, out, N);
}